// Round 6
// baseline (306.963 us; speedup 1.0000x reference)
//
#include <hip/hip_runtime.h>

#define MUL 16
#define NTILE 30          // 12 s-tiles + 12 pq-tiles + 6 t-tiles
#define NCHUNK 6

typedef __bf16 bf16x8 __attribute__((ext_vector_type(8)));
typedef float  f32x2  __attribute__((ext_vector_type(2)));
typedef float  f32x4  __attribute__((ext_vector_type(4)));

// Group schedule: 24 groups g, each = (u_g, vstart_g), covering 8 pair slots
// j=0..7 with v = vstart+j (valid while v<=15; pads have zero B columns).
//   u<=7: two groups: g=2u+h -> vstart = u + 8h
//   u>=8: one group:  g=16+(u-8) -> vstart = u
// Group g -> chunk c=g>>2, q-lane-group q=g&3.
__device__ __forceinline__ void group_uvs(int g, int& u, int& vs) {
    if (g < 16) { u = g >> 1; vs = u + ((g & 1) << 3); }
    else        { u = g - 8;  vs = u; }
}

// ---------------------------------------------------------------------------
// prep: one thread per 16-B B-fragment (tile,lane).  (unchanged)
// ---------------------------------------------------------------------------
__global__ void prep_weights(const float* __restrict__ w000,
                             const float* __restrict__ w101,
                             const float* __restrict__ w110,
                             const float* __restrict__ w112,
                             __bf16* __restrict__ wt) {
    const int gid = blockIdx.x * 256 + threadIdx.x;
    if (gid >= NTILE * 64) return;
    const int T = gid >> 6, lane = gid & 63;
    const int q = lane >> 4, w = lane & 15;

    const float A000   = 0.044194173824159216f;   // sqrt(1/(2*16*16))
    const float A110   = 0.025515518153991442f;   // A000/sqrt(3)
    const float A101   = 0.0625f;
    const float A112C1 = 0.044194173824159216f;   // A112/sqrt(10)

    bf16x8 frag = {};
    if (T < 12) {
        const int c = T >> 1, h = T & 1;
        int u, vs; group_uvs(4 * c + q, u, vs);
#pragma unroll
        for (int i = 0; i < 4; ++i) {
            const int v = vs + 4 * h + i;
            if (v < 16) {
                const int uvw = (u * MUL + v) * MUL + w;
                const int vuw = (v * MUL + u) * MUL + w;
                float f000, f110;
                if (u == v) { f000 = A000 * w000[uvw]; f110 = A110 * w110[uvw]; }
                else        { f000 = A000 * (w000[uvw] + w000[vuw]);
                              f110 = A110 * (w110[uvw] + w110[vuw]); }
                frag[2 * i]     = (__bf16)f000;
                frag[2 * i + 1] = (__bf16)f110;
            }
        }
    } else if (T < 24) {
        const int c = (T - 12) >> 1, h = (T - 12) & 1;
        int u, vs; group_uvs(4 * c + q, u, vs);
#pragma unroll
        for (int i = 0; i < 4; ++i) {
            const int v = vs + 4 * h + i;
            if (v < 16) {
                const int uvw = (u * MUL + v) * MUL + w;
                const int vuw = (v * MUL + u) * MUL + w;
                frag[2 * i]     = (__bf16)(A101 * w101[uvw]);
                frag[2 * i + 1] = (__bf16)((u == v) ? 0.f : A101 * w101[vuw]);
            }
        }
    } else {
        const int c = T - 24;
        int u, vs; group_uvs(4 * c + q, u, vs);
#pragma unroll
        for (int e = 0; e < 8; ++e) {
            const int v = vs + e;
            if (v < 16) {
                const int uvw = (u * MUL + v) * MUL + w;
                const int vuw = (v * MUL + u) * MUL + w;
                const float f112 = (u == v) ? A112C1 * w112[uvw]
                                            : A112C1 * (w112[uvw] + w112[vuw]);
                frag[e] = (__bf16)f112;
            }
        }
    }
    ((bf16x8*)wt)[T * 64 + lane] = frag;
}

// ---------------------------------------------------------------------------
// Main: persistent 256-thread blocks (4 INDEPENDENT waves, 16 nodes each),
// grid-stride over 64-node tiles.  Per-wave LDS slice (2304 f32) is a UNION:
// xq quad layout (16x68) during compute, epilogue image (16x144) after.
// No B-prefetch double-buffer (wtiles is 30 KB -> L1-resident after tile 0);
// amdgpu_waves_per_eu(4,4) pins the allocator at the LDS-implied occupancy
// so it uses the full 128-VGPR budget instead of spilling (r5 lesson).
// ---------------------------------------------------------------------------
#define SQ3f  1.7320508075688772f
#define ISQ3f 0.5773502691896258f

template<int J>
__device__ __forceinline__ void do_pair(int vs, const float* __restrict__ xrow,
        const float4 xu,
        bf16x8& fS, bf16x8& f0, bf16x8& f1, bf16x8& f2,
        bf16x8& t0, bf16x8& t1, bf16x8& t2, bf16x8& t3, bf16x8& t4) {
    int v = vs + J;
    v = v < 15 ? v : 15;                              // pads: B cols are zero
    const float4 xv = *(const float4*)(xrow + 4 * v);

    const f32x2 U01 = {xu.x, xu.y};   // (x0u, a0u)
    const f32x2 U23 = {xu.z, xu.w};   // (a1u, a2u)
    const f32x2 U10 = {xu.y, xu.x};
    const f32x2 V01 = {xv.x, xv.y};
    const f32x2 V23 = {xv.z, xv.w};
    const f32x2 V10 = {xv.y, xv.x};
    const f32x2 V32 = {xv.w, xv.z};

    const f32x2 P1 = U01 * V01;       // (s0,   o00)
    const f32x2 P2 = U23 * V23;       // (o11,  o22)
    const f32x2 P3 = U01 * V23;       // (f1vu, o02)
    const f32x2 P4 = U23 * V01;       // (f1uv, o20)
    const f32x2 P5 = U01 * V32;       // (f2vu, o01)
    const f32x2 P6 = U23 * V10;       // (o10,  f2uv)
    const f32x2 P7 = U23 * V32;       // (o12,  o21)
    const f32x2 P8 = U10 * V01;       // (f0uv, f0vu)

    const float o00 = P1[1], o11 = P2[0], o22 = P2[1];
    const float s1 = (o00 + o11) + o22;

    constexpr int s2 = (J & 3) * 2;
    fS[s2]     = (__bf16)P1[0];  fS[s2 + 1] = (__bf16)s1;
    f0[s2]     = (__bf16)P8[0];  f0[s2 + 1] = (__bf16)P8[1];
    f1[s2]     = (__bf16)P4[0];  f1[s2 + 1] = (__bf16)P3[0];
    f2[s2]     = (__bf16)P6[1];  f2[s2 + 1] = (__bf16)P5[0];
    t0[J] = (__bf16)(P5[1] + P6[0]);
    t1[J] = (__bf16)(P3[1] + P4[1]);
    t2[J] = (__bf16)(P7[0] + P7[1]);
    t3[J] = (__bf16)(o00 - o11);
    t4[J] = (__bf16)(SQ3f * o22 - ISQ3f * s1);
}

__launch_bounds__(256)
__attribute__((amdgpu_waves_per_eu(4, 4)))
__global__ void tsq_kernel(const float* __restrict__ feats,
                           const float* __restrict__ msgs,
                           const __bf16* __restrict__ wtiles,
                           float* __restrict__ out,
                           int ntiles) {
    // per-wave slice: UNION of xq (16 nodes x 68 f32 = 1088) and
    // epilogue image (16 x 144 = 2304).  4 waves x 2304 x 4B = 36864 B.
    __shared__ __align__(16) float smem[4][2304];

    const int tid  = threadIdx.x;
    const int lane = tid & 63;
    const int wid  = tid >> 6;
    float* sw = smem[wid];

    const int m = lane & 15, q = lane >> 4;
    const float* xrow = sw + m * 68;
    const bf16x8* wb = (const bf16x8*)wtiles;

    for (int tile = blockIdx.x; tile < ntiles; tile += gridDim.x) {
        const long long waveNode = (long long)tile * 64 + wid * 16;

        // ---- stage this wave's 16 nodes: thread (g*4+k, v) builds one quad ----
        {
            const int v = lane & 15, g = lane >> 4;
#pragma unroll
            for (int k = 0; k < 4; ++k) {
                const int nd = g * 4 + k;
                const float* fp = feats + (waveNode + nd) * 64;
                const float* mp = msgs  + (waveNode + nd) * 64;
                float4 qd;
                qd.x = fp[v]          + mp[v];
                qd.y = fp[16 + 3 * v] + mp[16 + 3 * v];
                qd.z = fp[17 + 3 * v] + mp[17 + 3 * v];
                qd.w = fp[18 + 3 * v] + mp[18 + 3 * v];
                *(float4*)&sw[nd * 68 + 4 * v] = qd;
            }
        }
        __syncthreads();

        f32x4 accS  = {0.f, 0.f, 0.f, 0.f};
        f32x4 accP0 = {0.f, 0.f, 0.f, 0.f};
        f32x4 accP1 = {0.f, 0.f, 0.f, 0.f};
        f32x4 accP2 = {0.f, 0.f, 0.f, 0.f};
        f32x4 accT0 = {0.f, 0.f, 0.f, 0.f};
        f32x4 accT1 = {0.f, 0.f, 0.f, 0.f};
        f32x4 accT2 = {0.f, 0.f, 0.f, 0.f};
        f32x4 accT3 = {0.f, 0.f, 0.f, 0.f};
        f32x4 accT4 = {0.f, 0.f, 0.f, 0.f};

#pragma unroll
        for (int c = 0; c < NCHUNK; ++c) {
            // B fragments: L1 hits after the first tile (wtiles = 30 KB)
            const bf16x8 bS0 = wb[(2 * c) * 64 + lane];
            const bf16x8 bS1 = wb[(2 * c + 1) * 64 + lane];
            const bf16x8 bP0 = wb[(12 + 2 * c) * 64 + lane];
            const bf16x8 bP1 = wb[(13 + 2 * c) * 64 + lane];
            const bf16x8 bT  = wb[(24 + c) * 64 + lane];

            // group g = 4c+q; c compile-time -> folds
            int u, vs;
            if (c < 4) { u = 2 * c + (q >> 1); vs = u + ((q & 1) << 3); }
            else       { u = 4 * c - 8 + q;    vs = u; }
            const float4 xu = *(const float4*)(xrow + 4 * u);   // ONE read/chunk

            bf16x8 t0 = {}, t1 = {}, t2 = {}, t3 = {}, t4 = {};
            {
                bf16x8 fS, f0, f1, f2;
                do_pair<0>(vs, xrow, xu, fS, f0, f1, f2, t0, t1, t2, t3, t4);
                do_pair<1>(vs, xrow, xu, fS, f0, f1, f2, t0, t1, t2, t3, t4);
                do_pair<2>(vs, xrow, xu, fS, f0, f1, f2, t0, t1, t2, t3, t4);
                do_pair<3>(vs, xrow, xu, fS, f0, f1, f2, t0, t1, t2, t3, t4);
                accS  = __builtin_amdgcn_mfma_f32_16x16x32_bf16(fS, bS0, accS,  0, 0, 0);
                accP0 = __builtin_amdgcn_mfma_f32_16x16x32_bf16(f0, bP0, accP0, 0, 0, 0);
                accP1 = __builtin_amdgcn_mfma_f32_16x16x32_bf16(f1, bP0, accP1, 0, 0, 0);
                accP2 = __builtin_amdgcn_mfma_f32_16x16x32_bf16(f2, bP0, accP2, 0, 0, 0);
            }
            {
                bf16x8 fS, f0, f1, f2;
                do_pair<4>(vs, xrow, xu, fS, f0, f1, f2, t0, t1, t2, t3, t4);
                do_pair<5>(vs, xrow, xu, fS, f0, f1, f2, t0, t1, t2, t3, t4);
                do_pair<6>(vs, xrow, xu, fS, f0, f1, f2, t0, t1, t2, t3, t4);
                do_pair<7>(vs, xrow, xu, fS, f0, f1, f2, t0, t1, t2, t3, t4);
                accS  = __builtin_amdgcn_mfma_f32_16x16x32_bf16(fS, bS1, accS,  0, 0, 0);
                accP0 = __builtin_amdgcn_mfma_f32_16x16x32_bf16(f0, bP1, accP0, 0, 0, 0);
                accP1 = __builtin_amdgcn_mfma_f32_16x16x32_bf16(f1, bP1, accP1, 0, 0, 0);
                accP2 = __builtin_amdgcn_mfma_f32_16x16x32_bf16(f2, bP1, accP2, 0, 0, 0);
            }
            accT0 = __builtin_amdgcn_mfma_f32_16x16x32_bf16(t0, bT, accT0, 0, 0, 0);
            accT1 = __builtin_amdgcn_mfma_f32_16x16x32_bf16(t1, bT, accT1, 0, 0, 0);
            accT2 = __builtin_amdgcn_mfma_f32_16x16x32_bf16(t2, bT, accT2, 0, 0, 0);
            accT3 = __builtin_amdgcn_mfma_f32_16x16x32_bf16(t3, bT, accT3, 0, 0, 0);
            accT4 = __builtin_amdgcn_mfma_f32_16x16x32_bf16(t4, bT, accT4, 0, 0, 0);
        }

        __syncthreads();   // all xq reads done before ep overwrites the union

        // ---- epilogue: scatter to LDS image (union with xq), coalesced out ----
        // C/D col = lane&15 = output idx w, row = q*4+r = node-in-wave
#pragma unroll
        for (int r = 0; r < 4; ++r) {
            float* eb = sw + (q * 4 + r) * 144;
            eb[m]              = accS[r];
            eb[16 + 3 * m + 0] = accP0[r];
            eb[16 + 3 * m + 1] = accP1[r];
            eb[16 + 3 * m + 2] = accP2[r];
            eb[64 + 5 * m + 0] = accT0[r];
            eb[64 + 5 * m + 1] = accT1[r];
            eb[64 + 5 * m + 2] = accT2[r];
            eb[64 + 5 * m + 3] = accT3[r];
            eb[64 + 5 * m + 4] = accT4[r];
        }
        __syncthreads();   // scatter visible before read-back

        {
            const float4* ep4 = (const float4*)sw;
            float4* ob4 = (float4*)(out + waveNode * 144);
#pragma unroll
            for (int l = 0; l < 9; ++l)
                ob4[l * 64 + lane] = ep4[l * 64 + lane];   // 1024 B/instr contiguous
        }
        __syncthreads();   // read-back done before next tile's staging
    }
}

extern "C" void kernel_launch(void* const* d_in, const int* in_sizes, int n_in,
                              void* d_out, int out_size, void* d_ws, size_t ws_size,
                              hipStream_t stream) {
    const float* feats = (const float*)d_in[0];
    const float* msgs  = (const float*)d_in[1];
    const float* w000  = (const float*)d_in[2];
    const float* w101  = (const float*)d_in[3];
    const float* w110  = (const float*)d_in[4];
    const float* w112  = (const float*)d_in[5];
    __bf16* wt = (__bf16*)d_ws;                 // 30*64*16 B = 30720 B
    float* out = (float*)d_out;

    const int n = in_sizes[0] / (4 * MUL);      // 131072 nodes
    const int ntiles = n / 64;                  // 2048 tiles of 64 nodes
    const int grid = ntiles < 1024 ? ntiles : 1024;   // 4 blocks/CU resident

    prep_weights<<<(NTILE * 64 + 255) / 256, 256, 0, stream>>>(w000, w101, w110, w112, wt);
    tsq_kernel<<<grid, 256, 0, stream>>>(feats, msgs, wt, out, ntiles);
}

// Round 7
// 254.132 us; speedup vs baseline: 1.2079x; 1.2079x over previous
//
#include <hip/hip_runtime.h>

#define MUL 16
#define NTILE 30          // 12 s-tiles + 12 pq-tiles + 6 t-tiles
#define NCHUNK 6

typedef __bf16 bf16x8 __attribute__((ext_vector_type(8)));
typedef float  f32x2  __attribute__((ext_vector_type(2)));
typedef float  f32x4  __attribute__((ext_vector_type(4)));

// Group schedule: 24 groups g, each = (u_g, vstart_g), covering 8 pair slots
// j=0..7 with v = vstart+j (valid while v<=15; pads have zero B columns).
//   u<=7: two groups: g=2u+h -> vstart = u + 8h
//   u>=8: one group:  g=16+(u-8) -> vstart = u
// Group g -> chunk c=g>>2, q-lane-group q=g&3.
__device__ __forceinline__ void group_uvs(int g, int& u, int& vs) {
    if (g < 16) { u = g >> 1; vs = u + ((g & 1) << 3); }
    else        { u = g - 8;  vs = u; }
}

// ---------------------------------------------------------------------------
// prep: one thread per 16-B B-fragment (tile,lane).  (unchanged)
// ---------------------------------------------------------------------------
__global__ void prep_weights(const float* __restrict__ w000,
                             const float* __restrict__ w101,
                             const float* __restrict__ w110,
                             const float* __restrict__ w112,
                             __bf16* __restrict__ wt) {
    const int gid = blockIdx.x * 256 + threadIdx.x;
    if (gid >= NTILE * 64) return;
    const int T = gid >> 6, lane = gid & 63;
    const int q = lane >> 4, w = lane & 15;

    const float A000   = 0.044194173824159216f;   // sqrt(1/(2*16*16))
    const float A110   = 0.025515518153991442f;   // A000/sqrt(3)
    const float A101   = 0.0625f;
    const float A112C1 = 0.044194173824159216f;   // A112/sqrt(10)

    bf16x8 frag = {};
    if (T < 12) {
        const int c = T >> 1, h = T & 1;
        int u, vs; group_uvs(4 * c + q, u, vs);
#pragma unroll
        for (int i = 0; i < 4; ++i) {
            const int v = vs + 4 * h + i;
            if (v < 16) {
                const int uvw = (u * MUL + v) * MUL + w;
                const int vuw = (v * MUL + u) * MUL + w;
                float f000, f110;
                if (u == v) { f000 = A000 * w000[uvw]; f110 = A110 * w110[uvw]; }
                else        { f000 = A000 * (w000[uvw] + w000[vuw]);
                              f110 = A110 * (w110[uvw] + w110[vuw]); }
                frag[2 * i]     = (__bf16)f000;
                frag[2 * i + 1] = (__bf16)f110;
            }
        }
    } else if (T < 24) {
        const int c = (T - 12) >> 1, h = (T - 12) & 1;
        int u, vs; group_uvs(4 * c + q, u, vs);
#pragma unroll
        for (int i = 0; i < 4; ++i) {
            const int v = vs + 4 * h + i;
            if (v < 16) {
                const int uvw = (u * MUL + v) * MUL + w;
                const int vuw = (v * MUL + u) * MUL + w;
                frag[2 * i]     = (__bf16)(A101 * w101[uvw]);
                frag[2 * i + 1] = (__bf16)((u == v) ? 0.f : A101 * w101[vuw]);
            }
        }
    } else {
        const int c = T - 24;
        int u, vs; group_uvs(4 * c + q, u, vs);
#pragma unroll
        for (int e = 0; e < 8; ++e) {
            const int v = vs + e;
            if (v < 16) {
                const int uvw = (u * MUL + v) * MUL + w;
                const int vuw = (v * MUL + u) * MUL + w;
                const float f112 = (u == v) ? A112C1 * w112[uvw]
                                            : A112C1 * (w112[uvw] + w112[vuw]);
                frag[e] = (__bf16)f112;
            }
        }
    }
    ((bf16x8*)wt)[T * 64 + lane] = frag;
}

// ---------------------------------------------------------------------------
// Main: 256-thread blocks = 4 INDEPENDENT waves, each owning 16 nodes.
// Non-persistent (grid = n/64): dispatch cost amortized 4x vs 1-wave blocks.
// __launch_bounds__(256, 4): min 4 waves/EU -> 128-VGPR budget (the verified
// mechanism; r4 (64,4)->92 VGPR no-spill, r6 attr form -> ignored, spilled).
// Per-wave LDS slice (2304 f32) is a UNION: xq quads (16x68) during compute,
// epilogue image (16x144) after.  4 x 9216 B = 36864 B -> 4 blocks/CU.
// ---------------------------------------------------------------------------
#define SQ3f  1.7320508075688772f
#define ISQ3f 0.5773502691896258f

template<int J>
__device__ __forceinline__ void do_pair(int vs, const float* __restrict__ xrow,
        const float4 xu,
        bf16x8& fS, bf16x8& f0, bf16x8& f1, bf16x8& f2,
        bf16x8& t0, bf16x8& t1, bf16x8& t2, bf16x8& t3, bf16x8& t4) {
    int v = vs + J;
    v = v < 15 ? v : 15;                              // pads: B cols are zero
    const float4 xv = *(const float4*)(xrow + 4 * v);

    const f32x2 U01 = {xu.x, xu.y};   // (x0u, a0u)
    const f32x2 U23 = {xu.z, xu.w};   // (a1u, a2u)
    const f32x2 U10 = {xu.y, xu.x};
    const f32x2 V01 = {xv.x, xv.y};
    const f32x2 V23 = {xv.z, xv.w};
    const f32x2 V10 = {xv.y, xv.x};
    const f32x2 V32 = {xv.w, xv.z};

    const f32x2 P1 = U01 * V01;       // (s0,   o00)
    const f32x2 P2 = U23 * V23;       // (o11,  o22)
    const f32x2 P3 = U01 * V23;       // (f1vu, o02)
    const f32x2 P4 = U23 * V01;       // (f1uv, o20)
    const f32x2 P5 = U01 * V32;       // (f2vu, o01)
    const f32x2 P6 = U23 * V10;       // (o10,  f2uv)
    const f32x2 P7 = U23 * V32;       // (o12,  o21)
    const f32x2 P8 = U10 * V01;       // (f0uv, f0vu)

    const float o00 = P1[1], o11 = P2[0], o22 = P2[1];
    const float s1 = (o00 + o11) + o22;

    constexpr int s2 = (J & 3) * 2;
    fS[s2]     = (__bf16)P1[0];  fS[s2 + 1] = (__bf16)s1;
    f0[s2]     = (__bf16)P8[0];  f0[s2 + 1] = (__bf16)P8[1];
    f1[s2]     = (__bf16)P4[0];  f1[s2 + 1] = (__bf16)P3[0];
    f2[s2]     = (__bf16)P6[1];  f2[s2 + 1] = (__bf16)P5[0];
    t0[J] = (__bf16)(P5[1] + P6[0]);
    t1[J] = (__bf16)(P3[1] + P4[1]);
    t2[J] = (__bf16)(P7[0] + P7[1]);
    t3[J] = (__bf16)(o00 - o11);
    t4[J] = (__bf16)(SQ3f * o22 - ISQ3f * s1);
}

__launch_bounds__(256, 4)
__global__ void tsq_kernel(const float* __restrict__ feats,
                           const float* __restrict__ msgs,
                           const __bf16* __restrict__ wtiles,
                           float* __restrict__ out) {
    // per-wave slice: UNION of xq (16 x 68 f32) and epilogue image (16 x 144)
    __shared__ __align__(16) float smem[4][2304];

    const int tid  = threadIdx.x;
    const int lane = tid & 63;
    const int wid  = tid >> 6;
    float* sw = smem[wid];

    const long long waveNode = (long long)blockIdx.x * 64 + wid * 16;

    // ---- stage this wave's 16 nodes: thread (g*4+k, v) builds one quad ----
    {
        const int v = lane & 15, g = lane >> 4;
#pragma unroll
        for (int k = 0; k < 4; ++k) {
            const int nd = g * 4 + k;
            const float* fp = feats + (waveNode + nd) * 64;
            const float* mp = msgs  + (waveNode + nd) * 64;
            float4 qd;
            qd.x = fp[v]          + mp[v];
            qd.y = fp[16 + 3 * v] + mp[16 + 3 * v];
            qd.z = fp[17 + 3 * v] + mp[17 + 3 * v];
            qd.w = fp[18 + 3 * v] + mp[18 + 3 * v];
            *(float4*)&sw[nd * 68 + 4 * v] = qd;
        }
    }
    __syncthreads();

    const int m = lane & 15, q = lane >> 4;
    const float* xrow = sw + m * 68;
    const bf16x8* wb = (const bf16x8*)wtiles;

    f32x4 accS  = {0.f, 0.f, 0.f, 0.f};
    f32x4 accP0 = {0.f, 0.f, 0.f, 0.f};
    f32x4 accP1 = {0.f, 0.f, 0.f, 0.f};
    f32x4 accP2 = {0.f, 0.f, 0.f, 0.f};
    f32x4 accT0 = {0.f, 0.f, 0.f, 0.f};
    f32x4 accT1 = {0.f, 0.f, 0.f, 0.f};
    f32x4 accT2 = {0.f, 0.f, 0.f, 0.f};
    f32x4 accT3 = {0.f, 0.f, 0.f, 0.f};
    f32x4 accT4 = {0.f, 0.f, 0.f, 0.f};

    // prefetch chunk 0's B-fragments (r4-proven double-buffer)
    bf16x8 bS0 = wb[0 * 64 + lane];
    bf16x8 bS1 = wb[1 * 64 + lane];
    bf16x8 bP0 = wb[12 * 64 + lane];
    bf16x8 bP1 = wb[13 * 64 + lane];
    bf16x8 bT  = wb[24 * 64 + lane];

#pragma unroll
    for (int c = 0; c < NCHUNK; ++c) {
        // issue next chunk's fragment loads first (hide L1/L2 latency)
        bf16x8 nS0 = {}, nS1 = {}, nP0 = {}, nP1 = {}, nT = {};
        if (c + 1 < NCHUNK) {
            nS0 = wb[(2 * c + 2) * 64 + lane];
            nS1 = wb[(2 * c + 3) * 64 + lane];
            nP0 = wb[(14 + 2 * c) * 64 + lane];
            nP1 = wb[(15 + 2 * c) * 64 + lane];
            nT  = wb[(25 + c) * 64 + lane];
        }

        // group g = 4c+q; c compile-time -> folds
        int u, vs;
        if (c < 4) { u = 2 * c + (q >> 1); vs = u + ((q & 1) << 3); }
        else       { u = 4 * c - 8 + q;    vs = u; }
        const float4 xu = *(const float4*)(xrow + 4 * u);   // ONE read/chunk

        bf16x8 t0 = {}, t1 = {}, t2 = {}, t3 = {}, t4 = {};
        {
            bf16x8 fS, f0, f1, f2;
            do_pair<0>(vs, xrow, xu, fS, f0, f1, f2, t0, t1, t2, t3, t4);
            do_pair<1>(vs, xrow, xu, fS, f0, f1, f2, t0, t1, t2, t3, t4);
            do_pair<2>(vs, xrow, xu, fS, f0, f1, f2, t0, t1, t2, t3, t4);
            do_pair<3>(vs, xrow, xu, fS, f0, f1, f2, t0, t1, t2, t3, t4);
            accS  = __builtin_amdgcn_mfma_f32_16x16x32_bf16(fS, bS0, accS,  0, 0, 0);
            accP0 = __builtin_amdgcn_mfma_f32_16x16x32_bf16(f0, bP0, accP0, 0, 0, 0);
            accP1 = __builtin_amdgcn_mfma_f32_16x16x32_bf16(f1, bP0, accP1, 0, 0, 0);
            accP2 = __builtin_amdgcn_mfma_f32_16x16x32_bf16(f2, bP0, accP2, 0, 0, 0);
        }
        {
            bf16x8 fS, f0, f1, f2;
            do_pair<4>(vs, xrow, xu, fS, f0, f1, f2, t0, t1, t2, t3, t4);
            do_pair<5>(vs, xrow, xu, fS, f0, f1, f2, t0, t1, t2, t3, t4);
            do_pair<6>(vs, xrow, xu, fS, f0, f1, f2, t0, t1, t2, t3, t4);
            do_pair<7>(vs, xrow, xu, fS, f0, f1, f2, t0, t1, t2, t3, t4);
            accS  = __builtin_amdgcn_mfma_f32_16x16x32_bf16(fS, bS1, accS,  0, 0, 0);
            accP0 = __builtin_amdgcn_mfma_f32_16x16x32_bf16(f0, bP1, accP0, 0, 0, 0);
            accP1 = __builtin_amdgcn_mfma_f32_16x16x32_bf16(f1, bP1, accP1, 0, 0, 0);
            accP2 = __builtin_amdgcn_mfma_f32_16x16x32_bf16(f2, bP1, accP2, 0, 0, 0);
        }
        accT0 = __builtin_amdgcn_mfma_f32_16x16x32_bf16(t0, bT, accT0, 0, 0, 0);
        accT1 = __builtin_amdgcn_mfma_f32_16x16x32_bf16(t1, bT, accT1, 0, 0, 0);
        accT2 = __builtin_amdgcn_mfma_f32_16x16x32_bf16(t2, bT, accT2, 0, 0, 0);
        accT3 = __builtin_amdgcn_mfma_f32_16x16x32_bf16(t3, bT, accT3, 0, 0, 0);
        accT4 = __builtin_amdgcn_mfma_f32_16x16x32_bf16(t4, bT, accT4, 0, 0, 0);

        bS0 = nS0; bS1 = nS1; bP0 = nP0; bP1 = nP1; bT = nT;
    }

    __syncthreads();   // all xq reads done before ep overwrites the union

    // ---- epilogue: scatter to LDS image (union with xq), coalesced out ----
    // C/D col = lane&15 = output idx w, row = q*4+r = node-in-wave
#pragma unroll
    for (int r = 0; r < 4; ++r) {
        float* eb = sw + (q * 4 + r) * 144;
        eb[m]              = accS[r];
        eb[16 + 3 * m + 0] = accP0[r];
        eb[16 + 3 * m + 1] = accP1[r];
        eb[16 + 3 * m + 2] = accP2[r];
        eb[64 + 5 * m + 0] = accT0[r];
        eb[64 + 5 * m + 1] = accT1[r];
        eb[64 + 5 * m + 2] = accT2[r];
        eb[64 + 5 * m + 3] = accT3[r];
        eb[64 + 5 * m + 4] = accT4[r];
    }
    __syncthreads();   // scatter visible before read-back

    {
        const float4* ep4 = (const float4*)sw;
        float4* ob4 = (float4*)(out + waveNode * 144);
#pragma unroll
        for (int l = 0; l < 9; ++l)
            ob4[l * 64 + lane] = ep4[l * 64 + lane];   // 1024 B/instr contiguous
    }
}

extern "C" void kernel_launch(void* const* d_in, const int* in_sizes, int n_in,
                              void* d_out, int out_size, void* d_ws, size_t ws_size,
                              hipStream_t stream) {
    const float* feats = (const float*)d_in[0];
    const float* msgs  = (const float*)d_in[1];
    const float* w000  = (const float*)d_in[2];
    const float* w101  = (const float*)d_in[3];
    const float* w110  = (const float*)d_in[4];
    const float* w112  = (const float*)d_in[5];
    __bf16* wt = (__bf16*)d_ws;                 // 30*64*16 B = 30720 B
    float* out = (float*)d_out;

    const int n = in_sizes[0] / (4 * MUL);      // 131072 nodes

    prep_weights<<<(NTILE * 64 + 255) / 256, 256, 0, stream>>>(w000, w101, w110, w112, wt);
    tsq_kernel<<<n / 64, 256, 0, stream>>>(feats, msgs, wt, out);
}

// Round 9
// 157.318 us; speedup vs baseline: 1.9512x; 1.6154x over previous
//
#include <hip/hip_runtime.h>

#define MUL 16
#define NTILE 30          // 12 s-tiles + 12 pq-tiles + 6 t-tiles
#define NCHUNK 6

typedef __bf16 bf16x8 __attribute__((ext_vector_type(8)));
typedef float  f32x2  __attribute__((ext_vector_type(2)));
typedef float  f32x4  __attribute__((ext_vector_type(4)));

// Group schedule: 24 groups g, each = (u_g, vstart_g), covering 8 pair slots
// j=0..7 with v = vstart+j (valid while v<=15; pads have zero B columns).
//   u<=7: two groups: g=2u+h -> vstart = u + 8h
//   u>=8: one group:  g=16+(u-8) -> vstart = u
// Group g -> chunk c=g>>2, q-lane-group q=g&3.
__device__ __forceinline__ void group_uvs(int g, int& u, int& vs) {
    if (g < 16) { u = g >> 1; vs = u + ((g & 1) << 3); }
    else        { u = g - 8;  vs = u; }
}

// ---------------------------------------------------------------------------
// prep: one thread per 16-B B-fragment (tile,lane).  (unchanged)
// ---------------------------------------------------------------------------
__global__ void prep_weights(const float* __restrict__ w000,
                             const float* __restrict__ w101,
                             const float* __restrict__ w110,
                             const float* __restrict__ w112,
                             __bf16* __restrict__ wt) {
    const int gid = blockIdx.x * 256 + threadIdx.x;
    if (gid >= NTILE * 64) return;
    const int T = gid >> 6, lane = gid & 63;
    const int q = lane >> 4, w = lane & 15;

    const float A000   = 0.044194173824159216f;   // sqrt(1/(2*16*16))
    const float A110   = 0.025515518153991442f;   // A000/sqrt(3)
    const float A101   = 0.0625f;
    const float A112C1 = 0.044194173824159216f;   // A112/sqrt(10)

    bf16x8 frag = {};
    if (T < 12) {
        const int c = T >> 1, h = T & 1;
        int u, vs; group_uvs(4 * c + q, u, vs);
#pragma unroll
        for (int i = 0; i < 4; ++i) {
            const int v = vs + 4 * h + i;
            if (v < 16) {
                const int uvw = (u * MUL + v) * MUL + w;
                const int vuw = (v * MUL + u) * MUL + w;
                float f000, f110;
                if (u == v) { f000 = A000 * w000[uvw]; f110 = A110 * w110[uvw]; }
                else        { f000 = A000 * (w000[uvw] + w000[vuw]);
                              f110 = A110 * (w110[uvw] + w110[vuw]); }
                frag[2 * i]     = (__bf16)f000;
                frag[2 * i + 1] = (__bf16)f110;
            }
        }
    } else if (T < 24) {
        const int c = (T - 12) >> 1, h = (T - 12) & 1;
        int u, vs; group_uvs(4 * c + q, u, vs);
#pragma unroll
        for (int i = 0; i < 4; ++i) {
            const int v = vs + 4 * h + i;
            if (v < 16) {
                const int uvw = (u * MUL + v) * MUL + w;
                const int vuw = (v * MUL + u) * MUL + w;
                frag[2 * i]     = (__bf16)(A101 * w101[uvw]);
                frag[2 * i + 1] = (__bf16)((u == v) ? 0.f : A101 * w101[vuw]);
            }
        }
    } else {
        const int c = T - 24;
        int u, vs; group_uvs(4 * c + q, u, vs);
#pragma unroll
        for (int e = 0; e < 8; ++e) {
            const int v = vs + e;
            if (v < 16) {
                const int uvw = (u * MUL + v) * MUL + w;
                const int vuw = (v * MUL + u) * MUL + w;
                const float f112 = (u == v) ? A112C1 * w112[uvw]
                                            : A112C1 * (w112[uvw] + w112[vuw]);
                frag[e] = (__bf16)f112;
            }
        }
    }
    ((bf16x8*)wt)[T * 64 + lane] = frag;
}

// ---------------------------------------------------------------------------
// Main: 256-thread blocks = 4 INDEPENDENT waves, each owning 16 nodes.
// __launch_bounds__(256, 3): the empirically-CLEAN bound (r1: 80 VGPR, ideal
// traffic).  (256,4) and the waves_per_eu attr both produced a 64-arch-VGPR
// cap + scratch spill loop (r5/r6/r7 — unified VGPR/AGPR split halves the
// arch budget).  No B double-buffer: wtiles (30 KB) is L1-resident after the
// first tile and 12 waves/CU of TLP hide L1 latency; dropping it removes
// 40 live VGPRs of spill pressure.
// Per-wave LDS slice (2304 f32) is a UNION: xq quads (16x68) during compute,
// epilogue image (16x144) after.  4 x 9216 B = 36864 B.
// ---------------------------------------------------------------------------
#define SQ3f  1.7320508075688772f
#define ISQ3f 0.5773502691896258f

template<int J>
__device__ __forceinline__ void do_pair(int vs, const float* __restrict__ xrow,
        const float4 xu,
        bf16x8& fS, bf16x8& f0, bf16x8& f1, bf16x8& f2,
        bf16x8& t0, bf16x8& t1, bf16x8& t2, bf16x8& t3, bf16x8& t4) {
    int v = vs + J;
    v = v < 15 ? v : 15;                              // pads: B cols are zero
    const float4 xv = *(const float4*)(xrow + 4 * v);

    const f32x2 U01 = {xu.x, xu.y};   // (x0u, a0u)
    const f32x2 U23 = {xu.z, xu.w};   // (a1u, a2u)
    const f32x2 U10 = {xu.y, xu.x};
    const f32x2 V01 = {xv.x, xv.y};
    const f32x2 V23 = {xv.z, xv.w};
    const f32x2 V10 = {xv.y, xv.x};
    const f32x2 V32 = {xv.w, xv.z};

    const f32x2 P1 = U01 * V01;       // (s0,   o00)
    const f32x2 P2 = U23 * V23;       // (o11,  o22)
    const f32x2 P3 = U01 * V23;       // (f1vu, o02)
    const f32x2 P4 = U23 * V01;       // (f1uv, o20)
    const f32x2 P5 = U01 * V32;       // (f2vu, o01)
    const f32x2 P6 = U23 * V10;       // (o10,  f2uv)
    const f32x2 P7 = U23 * V32;       // (o12,  o21)
    const f32x2 P8 = U10 * V01;       // (f0uv, f0vu)

    const float o00 = P1[1], o11 = P2[0], o22 = P2[1];
    const float s1 = (o00 + o11) + o22;

    constexpr int s2 = (J & 3) * 2;
    fS[s2]     = (__bf16)P1[0];  fS[s2 + 1] = (__bf16)s1;
    f0[s2]     = (__bf16)P8[0];  f0[s2 + 1] = (__bf16)P8[1];
    f1[s2]     = (__bf16)P4[0];  f1[s2 + 1] = (__bf16)P3[0];
    f2[s2]     = (__bf16)P6[1];  f2[s2 + 1] = (__bf16)P5[0];
    t0[J] = (__bf16)(P5[1] + P6[0]);
    t1[J] = (__bf16)(P3[1] + P4[1]);
    t2[J] = (__bf16)(P7[0] + P7[1]);
    t3[J] = (__bf16)(o00 - o11);
    t4[J] = (__bf16)(SQ3f * o22 - ISQ3f * s1);
}

__launch_bounds__(256, 3)
__global__ void tsq_kernel(const float* __restrict__ feats,
                           const float* __restrict__ msgs,
                           const __bf16* __restrict__ wtiles,
                           float* __restrict__ out) {
    // per-wave slice: UNION of xq (16 x 68 f32) and epilogue image (16 x 144)
    __shared__ __align__(16) float smem[4][2304];

    const int tid  = threadIdx.x;
    const int lane = tid & 63;
    const int wid  = tid >> 6;
    float* sw = smem[wid];

    const long long waveNode = (long long)blockIdx.x * 64 + wid * 16;

    // ---- stage this wave's 16 nodes: thread (g*4+k, v) builds one quad ----
    {
        const int v = lane & 15, g = lane >> 4;
#pragma unroll
        for (int k = 0; k < 4; ++k) {
            const int nd = g * 4 + k;
            const float* fp = feats + (waveNode + nd) * 64;
            const float* mp = msgs  + (waveNode + nd) * 64;
            float4 qd;
            qd.x = fp[v]          + mp[v];
            qd.y = fp[16 + 3 * v] + mp[16 + 3 * v];
            qd.z = fp[17 + 3 * v] + mp[17 + 3 * v];
            qd.w = fp[18 + 3 * v] + mp[18 + 3 * v];
            *(float4*)&sw[nd * 68 + 4 * v] = qd;
        }
    }
    __syncthreads();

    const int m = lane & 15, q = lane >> 4;
    const float* xrow = sw + m * 68;
    const bf16x8* wb = (const bf16x8*)wtiles;

    f32x4 accS  = {0.f, 0.f, 0.f, 0.f};
    f32x4 accP0 = {0.f, 0.f, 0.f, 0.f};
    f32x4 accP1 = {0.f, 0.f, 0.f, 0.f};
    f32x4 accP2 = {0.f, 0.f, 0.f, 0.f};
    f32x4 accT0 = {0.f, 0.f, 0.f, 0.f};
    f32x4 accT1 = {0.f, 0.f, 0.f, 0.f};
    f32x4 accT2 = {0.f, 0.f, 0.f, 0.f};
    f32x4 accT3 = {0.f, 0.f, 0.f, 0.f};
    f32x4 accT4 = {0.f, 0.f, 0.f, 0.f};

#pragma unroll
    for (int c = 0; c < NCHUNK; ++c) {
        // B fragments: L1 hits after the first tile (wtiles = 30 KB)
        const bf16x8 bS0 = wb[(2 * c) * 64 + lane];
        const bf16x8 bS1 = wb[(2 * c + 1) * 64 + lane];
        const bf16x8 bP0 = wb[(12 + 2 * c) * 64 + lane];
        const bf16x8 bP1 = wb[(13 + 2 * c) * 64 + lane];
        const bf16x8 bT  = wb[(24 + c) * 64 + lane];

        // group g = 4c+q; c compile-time -> folds
        int u, vs;
        if (c < 4) { u = 2 * c + (q >> 1); vs = u + ((q & 1) << 3); }
        else       { u = 4 * c - 8 + q;    vs = u; }
        const float4 xu = *(const float4*)(xrow + 4 * u);   // ONE read/chunk

        bf16x8 t0 = {}, t1 = {}, t2 = {}, t3 = {}, t4 = {};
        {
            bf16x8 fS, f0, f1, f2;
            do_pair<0>(vs, xrow, xu, fS, f0, f1, f2, t0, t1, t2, t3, t4);
            do_pair<1>(vs, xrow, xu, fS, f0, f1, f2, t0, t1, t2, t3, t4);
            do_pair<2>(vs, xrow, xu, fS, f0, f1, f2, t0, t1, t2, t3, t4);
            do_pair<3>(vs, xrow, xu, fS, f0, f1, f2, t0, t1, t2, t3, t4);
            accS  = __builtin_amdgcn_mfma_f32_16x16x32_bf16(fS, bS0, accS,  0, 0, 0);
            accP0 = __builtin_amdgcn_mfma_f32_16x16x32_bf16(f0, bP0, accP0, 0, 0, 0);
            accP1 = __builtin_amdgcn_mfma_f32_16x16x32_bf16(f1, bP0, accP1, 0, 0, 0);
            accP2 = __builtin_amdgcn_mfma_f32_16x16x32_bf16(f2, bP0, accP2, 0, 0, 0);
        }
        {
            bf16x8 fS, f0, f1, f2;
            do_pair<4>(vs, xrow, xu, fS, f0, f1, f2, t0, t1, t2, t3, t4);
            do_pair<5>(vs, xrow, xu, fS, f0, f1, f2, t0, t1, t2, t3, t4);
            do_pair<6>(vs, xrow, xu, fS, f0, f1, f2, t0, t1, t2, t3, t4);
            do_pair<7>(vs, xrow, xu, fS, f0, f1, f2, t0, t1, t2, t3, t4);
            accS  = __builtin_amdgcn_mfma_f32_16x16x32_bf16(fS, bS1, accS,  0, 0, 0);
            accP0 = __builtin_amdgcn_mfma_f32_16x16x32_bf16(f0, bP1, accP0, 0, 0, 0);
            accP1 = __builtin_amdgcn_mfma_f32_16x16x32_bf16(f1, bP1, accP1, 0, 0, 0);
            accP2 = __builtin_amdgcn_mfma_f32_16x16x32_bf16(f2, bP1, accP2, 0, 0, 0);
        }
        accT0 = __builtin_amdgcn_mfma_f32_16x16x32_bf16(t0, bT, accT0, 0, 0, 0);
        accT1 = __builtin_amdgcn_mfma_f32_16x16x32_bf16(t1, bT, accT1, 0, 0, 0);
        accT2 = __builtin_amdgcn_mfma_f32_16x16x32_bf16(t2, bT, accT2, 0, 0, 0);
        accT3 = __builtin_amdgcn_mfma_f32_16x16x32_bf16(t3, bT, accT3, 0, 0, 0);
        accT4 = __builtin_amdgcn_mfma_f32_16x16x32_bf16(t4, bT, accT4, 0, 0, 0);
    }

    __syncthreads();   // all xq reads done before ep overwrites the union

    // ---- epilogue: scatter to LDS image (union with xq), coalesced out ----
    // C/D col = lane&15 = output idx w, row = q*4+r = node-in-wave
#pragma unroll
    for (int r = 0; r < 4; ++r) {
        float* eb = sw + (q * 4 + r) * 144;
        eb[m]              = accS[r];
        eb[16 + 3 * m + 0] = accP0[r];
        eb[16 + 3 * m + 1] = accP1[r];
        eb[16 + 3 * m + 2] = accP2[r];
        eb[64 + 5 * m + 0] = accT0[r];
        eb[64 + 5 * m + 1] = accT1[r];
        eb[64 + 5 * m + 2] = accT2[r];
        eb[64 + 5 * m + 3] = accT3[r];
        eb[64 + 5 * m + 4] = accT4[r];
    }
    __syncthreads();   // scatter visible before read-back

    {
        const float4* ep4 = (const float4*)sw;
        float4* ob4 = (float4*)(out + waveNode * 144);
#pragma unroll
        for (int l = 0; l < 9; ++l)
            ob4[l * 64 + lane] = ep4[l * 64 + lane];   // 1024 B/instr contiguous
    }
}

extern "C" void kernel_launch(void* const* d_in, const int* in_sizes, int n_in,
                              void* d_out, int out_size, void* d_ws, size_t ws_size,
                              hipStream_t stream) {
    const float* feats = (const float*)d_in[0];
    const float* msgs  = (const float*)d_in[1];
    const float* w000  = (const float*)d_in[2];
    const float* w101  = (const float*)d_in[3];
    const float* w110  = (const float*)d_in[4];
    const float* w112  = (const float*)d_in[5];
    __bf16* wt = (__bf16*)d_ws;                 // 30*64*16 B = 30720 B
    float* out = (float*)d_out;

    const int n = in_sizes[0] / (4 * MUL);      // 131072 nodes

    prep_weights<<<(NTILE * 64 + 255) / 256, 256, 0, stream>>>(w000, w101, w110, w112, wt);
    tsq_kernel<<<n / 64, 256, 0, stream>>>(feats, msgs, wt, out);
}